// Round 2
// baseline (6487.490 us; speedup 1.0000x reference)
//
#include <hip/hip_runtime.h>
#include <cstddef>
#include <cstdint>

// Problem constants (SerGINE)
#define NA_C 200000
#define NF_C 50000
#define EA_C 800000
#define EF_C 200000
#define NG_C 4096
#define DD 128   // node feature dim
#define HH 256   // hidden dim (2*D)

// ---------------------------------------------------------------------------
// Generic fp32 GEMM: C = op(A) @ W + bias [+ Cadd]
//   op(A): v = A[m,k]; if Aadd v += Aadd[m,k]; if rowscale v *= rowscale[m];
//          if iscale  v = relu(v*iscale[k] + ishift[k])   (fused BN+relu read)
// 128x128 tile, BK=8, 256 threads, 8x8 micro-tile per thread.
// ---------------------------------------------------------------------------
__global__ __launch_bounds__(256) void gemm_f32(
    const float* __restrict__ A, const float* __restrict__ Aadd,
    const float* __restrict__ rowscale,
    const float* __restrict__ iscale, const float* __restrict__ ishift,
    const float* __restrict__ W, const float* __restrict__ bias,
    const float* __restrict__ Cadd, float* __restrict__ C,
    int M, int K, int N)
{
    __shared__ float As[8][132];
    __shared__ float Bs[8][132];
    const int tid = threadIdx.x;
    const int tx = tid & 15;
    const int ty = tid >> 4;
    const int m0 = blockIdx.y * 128;
    const int n0 = blockIdx.x * 128;

    float acc[8][8];
#pragma unroll
    for (int i = 0; i < 8; ++i)
#pragma unroll
        for (int j = 0; j < 8; ++j) acc[i][j] = 0.f;

    const int ar = tid >> 1;
    const int ak = (tid & 1) * 4;
    const int br = tid >> 5;
    const int bc = (tid & 31) * 4;

    for (int k0 = 0; k0 < K; k0 += 8) {
#pragma unroll
        for (int j = 0; j < 4; ++j) {
            int m = m0 + ar, k = k0 + ak + j;
            float v = 0.f;
            if (m < M && k < K) {
                size_t idx = (size_t)m * K + k;
                v = A[idx];
                if (Aadd) v += Aadd[idx];
                if (rowscale) v *= rowscale[m];
                if (iscale) v = fmaxf(fmaf(v, iscale[k], ishift[k]), 0.f);
            }
            As[ak + j][ar] = v;
        }
        {
            int k = k0 + br;
            float4 v = make_float4(0.f, 0.f, 0.f, 0.f);
            if (k < K) v = *(const float4*)&W[(size_t)k * N + n0 + bc];
            *(float4*)&Bs[br][bc] = v;
        }
        __syncthreads();
#pragma unroll
        for (int kk = 0; kk < 8; ++kk) {
            float a[8], b[8];
            *(float4*)&a[0] = *(const float4*)&As[kk][tx * 8];
            *(float4*)&a[4] = *(const float4*)&As[kk][tx * 8 + 4];
            *(float4*)&b[0] = *(const float4*)&Bs[kk][ty * 8];
            *(float4*)&b[4] = *(const float4*)&Bs[kk][ty * 8 + 4];
#pragma unroll
            for (int i = 0; i < 8; ++i)
#pragma unroll
                for (int j = 0; j < 8; ++j)
                    acc[i][j] = fmaf(a[i], b[j], acc[i][j]);
        }
        __syncthreads();
    }

    const int row0 = m0 + tx * 8, col0 = n0 + ty * 8;
#pragma unroll
    for (int i = 0; i < 8; ++i) {
        int m = row0 + i;
        if (m < M) {
            size_t base = (size_t)m * N + col0;
#pragma unroll
            for (int j = 0; j < 8; ++j) {
                float v = acc[i][j] + bias[col0 + j];
                if (Cadd) v += Cadd[base + j];
                C[base + j] = v;
            }
        }
    }
}

static inline void gemm_launch(hipStream_t s,
    const float* A, const float* Aadd, const float* rowscale,
    const float* iscale, const float* ishift,
    const float* W, const float* bias, const float* Cadd, float* C,
    int M, int K, int N)
{
    dim3 grid(N / 128, (M + 127) / 128);
    gemm_f32<<<grid, dim3(256), 0, s>>>(A, Aadd, rowscale, iscale, ishift, W, bias, Cadd, C, M, K, N);
}

// ---------------------------------------------------------------------------
// CSR build: histogram -> single-block scan -> fill (idx -> bucket-sorted ids)
// ---------------------------------------------------------------------------
__global__ void hist_k(const int* __restrict__ idx, int n, int* __restrict__ deg)
{
    int i = blockIdx.x * 256 + threadIdx.x;
    if (i < n) atomicAdd(&deg[idx[i]], 1);
}

__global__ __launch_bounds__(1024) void scan_k(const int* __restrict__ deg,
                                               int* __restrict__ rowptr, int n)
{
    __shared__ int ss[1024];
    const int t = threadIdx.x;
    const int chunk = (n + 1023) >> 10;
    const int lo = min(t * chunk, n), hi = min(lo + chunk, n);
    int s = 0;
    for (int i = lo; i < hi; ++i) s += deg[i];
    ss[t] = s;
    __syncthreads();
    for (int off = 1; off < 1024; off <<= 1) {
        int v = (t >= off) ? ss[t - off] : 0;
        __syncthreads();
        ss[t] += v;
        __syncthreads();
    }
    int run = t ? ss[t - 1] : 0;
    for (int i = lo; i < hi; ++i) { rowptr[i] = run; run += deg[i]; }
    if (t == 1023) rowptr[n] = ss[1023];
}

__global__ void fill_k(const int* __restrict__ idx, int n,
                       int* __restrict__ cursor, int* __restrict__ csr)
{
    int i = blockIdx.x * 256 + threadIdx.x;
    if (i < n) {
        int p = atomicAdd(&cursor[idx[i]], 1);
        csr[p] = i;
    }
}

static void build_csr(hipStream_t s, const int* idx, int n_entries, int n_buckets,
                      int* rowptr, int* cursor, int* csr)
{
    hipMemsetAsync(cursor, 0, (size_t)n_buckets * 4, s);
    hist_k<<<dim3((n_entries + 255) / 256), dim3(256), 0, s>>>(idx, n_entries, cursor);
    scan_k<<<dim3(1), dim3(1024), 0, s>>>(cursor, rowptr, n_buckets);
    hipMemcpyAsync(cursor, rowptr, (size_t)n_buckets * 4, hipMemcpyDeviceToDevice, s);
    fill_k<<<dim3((n_entries + 255) / 256), dim3(256), 0, s>>>(idx, n_entries, cursor, csr);
}

// ---------------------------------------------------------------------------
// Atom GINE aggregation (gather, no atomics):
//   out[v] = x[v] + sum_{e: dst[e]==v} relu(x[src[e]] + attr[e] @ Wm + bm)
// Edge MLP (11x128) in LDS; one 128-lane slot per node, 2 nodes per block.
// ---------------------------------------------------------------------------
__global__ __launch_bounds__(256) void gine_agg_atom(
    const float* __restrict__ x, const float* __restrict__ attr,
    const int* __restrict__ srcv, const int* __restrict__ csr,
    const int* __restrict__ rowptr,
    const float* __restrict__ Wm, const float* __restrict__ bm,
    float* __restrict__ out, int n)
{
    __shared__ float sW[11 * 128];
    __shared__ float sb[128];
    for (int i = threadIdx.x; i < 11 * 128; i += 256) sW[i] = Wm[i];
    if (threadIdx.x < 128) sb[threadIdx.x] = bm[threadIdx.x];
    __syncthreads();
    const int lane = threadIdx.x & 127;
    const int v = blockIdx.x * 2 + (threadIdx.x >> 7);
    if (v >= n) return;
    float acc = x[(size_t)v * 128 + lane];
    const int e1 = rowptr[v + 1];
    for (int e = rowptr[v]; e < e1; ++e) {
        const int eid = csr[e];
        const float* arow = attr + (size_t)eid * 11;
        float m = sb[lane];
#pragma unroll
        for (int k = 0; k < 11; ++k) m = fmaf(arow[k], sW[k * 128 + lane], m);
        m += x[(size_t)srcv[eid] * 128 + lane];
        acc += fmaxf(m, 0.f);
    }
    out[(size_t)v * 128 + lane] = acc;
}

// fg GINE aggregation with precomputed edge embeddings (eemb rows gathered):
__global__ __launch_bounds__(256) void gine_agg_pre(
    const float* __restrict__ x, const float* __restrict__ eemb,
    const int* __restrict__ srcv, const int* __restrict__ csr,
    const int* __restrict__ rowptr, float* __restrict__ out, int n)
{
    const int lane = threadIdx.x & 127;
    const int v = blockIdx.x * 2 + (threadIdx.x >> 7);
    if (v >= n) return;
    float acc = x[(size_t)v * 128 + lane];
    const int e1 = rowptr[v + 1];
    for (int e = rowptr[v]; e < e1; ++e) {
        const int eid = csr[e];
        float m = eemb[(size_t)eid * 128 + lane] + x[(size_t)srcv[eid] * 128 + lane];
        acc += fmaxf(m, 0.f);
    }
    out[(size_t)v * 128 + lane] = acc;
}

// segment mean via CSR gather: out[b] = mean over entries i in bucket b of
//   x[map ? map[i] : i]
__global__ __launch_bounds__(256) void seg_mean_k(
    const float* __restrict__ x, const int* __restrict__ map,
    const int* __restrict__ csr, const int* __restrict__ rowptr,
    float* __restrict__ out, int n)
{
    const int lane = threadIdx.x & 127;
    const int v = blockIdx.x * 2 + (threadIdx.x >> 7);
    if (v >= n) return;
    const int e0 = rowptr[v], e1 = rowptr[v + 1];
    float acc = 0.f;
    for (int e = e0; e < e1; ++e) {
        int r = csr[e];
        if (map) r = map[r];
        acc += x[(size_t)r * 128 + lane];
    }
    out[(size_t)v * 128 + lane] = acc / fmaxf((float)(e1 - e0), 1.f);
}

// ---------------------------------------------------------------------------
// BN helpers (two-pass)
// ---------------------------------------------------------------------------
__global__ void colstats(const float* __restrict__ X, int M, int N,
                         float* __restrict__ sum, float* __restrict__ sumsq)
{
    int c = threadIdx.x;
    int r0 = blockIdx.x * 128;
    int rend = min(r0 + 128, M);
    float s = 0.f, q = 0.f;
    for (int r = r0; r < rend; ++r) {
        float v = X[(size_t)r * N + c];
        s += v;
        q = fmaf(v, v, q);
    }
    atomicAdd(&sum[c], s);
    atomicAdd(&sumsq[c], q);
}

__global__ void bn_finalize(const float* __restrict__ sum, const float* __restrict__ sumsq,
                            const float* __restrict__ g, const float* __restrict__ be,
                            float minv, float* __restrict__ sc, float* __restrict__ sh, int N)
{
    int c = threadIdx.x;
    if (c < N) {
        float m = sum[c] * minv;
        float v = fmaxf(sumsq[c] * minv - m * m, 0.f);
        float s = g[c] * rsqrtf(v + 1e-5f);
        sc[c] = s;
        sh[c] = fmaf(-m, s, be[c]);
    }
}

__global__ void bn_apply(float* __restrict__ X, const float* __restrict__ sc,
                         const float* __restrict__ sh, int relu, size_t n4)
{
    size_t i = (size_t)blockIdx.x * 256 + threadIdx.x;
    if (i >= n4) return;
    size_t base = i * 4;
    int c = (int)(base & 127);
    float4 v = *(float4*)&X[base];
    v.x = fmaf(v.x, sc[c],     sh[c]);
    v.y = fmaf(v.y, sc[c + 1], sh[c + 1]);
    v.z = fmaf(v.z, sc[c + 2], sh[c + 2]);
    v.w = fmaf(v.w, sc[c + 3], sh[c + 3]);
    if (relu) {
        v.x = fmaxf(v.x, 0.f); v.y = fmaxf(v.y, 0.f);
        v.z = fmaxf(v.z, 0.f); v.w = fmaxf(v.w, 0.f);
    }
    *(float4*)&X[base] = v;
}

// ---------------------------------------------------------------------------
// WS layout: three 102.4 MB slots S0/S1/S2 (ping-pong h, hn, t spans 2 slots).
//   atom layer p=0: h@S0  hn@S2  t@S0S1  hnew@S2
//   atom layer p=1: h@S2  hn@S0  t@S1S2  hnew@S0
// Atom CSR: past 3 slots if ws allows (built once), else rebuilt per layer
// into the then-free S1. BN stats live in the tail of d_out (overwritten by
// the final seg_mean). fg-phase buffers tile S0/S1/S2 as commented below.
// ---------------------------------------------------------------------------
extern "C" void kernel_launch(void* const* d_in, const int* in_sizes, int n_in,
                              void* d_out, int out_size, void* d_ws, size_t ws_size,
                              hipStream_t stream)
{
    const float* atom_x        = (const float*)d_in[0];
    const float* fg_x          = (const float*)d_in[1];
    const float* atom_edge_attr= (const float*)d_in[2];
    const float* fg_edge_attr  = (const float*)d_in[3];
    const float* atom_emb_W    = (const float*)d_in[4];
    const float* atom_emb_b    = (const float*)d_in[5];
    const float* fg_emb_W      = (const float*)d_in[6];
    const float* fg_emb_b      = (const float*)d_in[7];
    const float* bond_W        = (const float*)d_in[8];
    const float* bond_b        = (const float*)d_in[9];
    const float* ag_W1         = (const float*)d_in[10];
    const float* ag_b1         = (const float*)d_in[11];
    const float* ag_g1         = (const float*)d_in[12];
    const float* ag_be1        = (const float*)d_in[13];
    const float* ag_W2         = (const float*)d_in[14];
    const float* ag_b2         = (const float*)d_in[15];
    const float* abn_g         = (const float*)d_in[16];
    const float* abn_b         = (const float*)d_in[17];
    const float* fge_W         = (const float*)d_in[18];
    const float* fge_b         = (const float*)d_in[19];
    const float* fg_W1         = (const float*)d_in[20];
    const float* fg_b1         = (const float*)d_in[21];
    const float* fg_g1         = (const float*)d_in[22];
    const float* fg_be1        = (const float*)d_in[23];
    const float* fg_W2         = (const float*)d_in[24];
    const float* fg_b2         = (const float*)d_in[25];
    const float* fbn_g         = (const float*)d_in[26];
    const float* fbn_b         = (const float*)d_in[27];
    const float* a2f_W         = (const float*)d_in[28];
    const float* a2f_b         = (const float*)d_in[29];
    const int*   aei           = (const int*)d_in[30];
    const int*   fei           = (const int*)d_in[31];
    const int*   atom_idx      = (const int*)d_in[32];
    const int*   fg_idx        = (const int*)d_in[33];
    const int*   fg_batch      = (const int*)d_in[34];
    const int *asrc = aei, *adst = aei + EA_C;
    const int *fsrc = fei, *fdst = fei + EF_C;

    float* ws = (float*)d_ws;
    const size_t SLOT = (size_t)NA_C * DD;     // 25.6M floats = 102.4 MB
    float* S0 = ws;
    float* S1 = ws + SLOT;
    float* S2 = ws + 2 * SLOT;

    // BN stats scratch in tail of d_out (2 MB total; final write covers it)
    float* sm    = (float*)d_out + (size_t)NG_C * DD - 2048;
    float* s_sum = sm;
    float* s_sq  = sm + 256;
    float* s_sc  = sm + 512;
    float* s_sh  = sm + 768;

    // atom CSR: persistent past the slots if ws is roomy, else rebuilt per
    // layer into S1 (free during aggregation at both parities)
    const bool roomy = ws_size >= ((size_t)330 << 20);
    int* aR = roomy ? (int*)(ws + 3 * SLOT) : (int*)S1;   // rowptr  NA+1
    int* aC = aR + (NA_C + 1);                            // cursor  NA
    int* aE = aC + NA_C;                                  // edge ids EA
    if (roomy) build_csr(stream, adst, EA_C, NA_C, aR, aC, aE);

    // 1) atom embedding: h = atom_x @ atom_emb_W + b   -> S0
    gemm_launch(stream, atom_x, nullptr, nullptr, nullptr, nullptr,
                atom_emb_W, atom_emb_b, nullptr, S0, NA_C, 101, DD);

    // 2) three atom GINE layers
    float* hcur = S0;
    for (int i = 0; i < 3; ++i) {
        float* hn = (hcur == S0) ? S2 : S0;
        float* t  = (hcur == S0) ? S0 : S1;   // spans 2 slots
        if (!roomy) build_csr(stream, adst, EA_C, NA_C, aR, aC, aE);
        gine_agg_atom<<<dim3((NA_C + 1) / 2), dim3(256), 0, stream>>>(
            hcur, atom_edge_attr, asrc, aE, aR,
            bond_W + (size_t)i * 11 * DD, bond_b + i * DD, hn, NA_C);
        gemm_launch(stream, hn, nullptr, nullptr, nullptr, nullptr,
                    ag_W1 + (size_t)i * DD * HH, ag_b1 + i * HH, nullptr, t, NA_C, DD, HH);
        hipMemsetAsync(s_sum, 0, 512 * sizeof(float), stream);
        colstats<<<dim3((NA_C + 127) / 128), dim3(HH), 0, stream>>>(t, NA_C, HH, s_sum, s_sq);
        bn_finalize<<<dim3(1), dim3(HH), 0, stream>>>(
            s_sum, s_sq, ag_g1 + i * HH, ag_be1 + i * HH, 1.f / NA_C, s_sc, s_sh, HH);
        // hnew = relu(bn(t)) @ W2 + b2  (bn+relu fused into GEMM A-read) -> hn slot
        gemm_launch(stream, t, nullptr, nullptr, s_sc, s_sh,
                    ag_W2 + (size_t)i * HH * DD, ag_b2 + i * DD, nullptr, hn, NA_C, HH, DD);
        hipMemsetAsync(s_sum, 0, 512 * sizeof(float), stream);
        colstats<<<dim3((NA_C + 127) / 128), dim3(DD), 0, stream>>>(hn, NA_C, DD, s_sum, s_sq);
        bn_finalize<<<dim3(1), dim3(DD), 0, stream>>>(
            s_sum, s_sq, abn_g + i * DD, abn_b + i * DD, 1.f / NA_C, s_sc, s_sh, DD);
        bn_apply<<<dim3((NA_C * DD / 4 + 255) / 256), dim3(256), 0, stream>>>(
            hn, s_sc, s_sh, (int)(i != 2), (size_t)NA_C * DD / 4);
        hcur = hn;
    }
    // hcur == S2 here

    // 3) a2f: means = seg_mean(h[atom_idx], fg_idx, NF) -> S0[0, NF*DD)
    //    a2f CSR transient in S1 (dead before g is written there)
    {
        int* xR = (int*)S1;
        int* xC = xR + (NF_C + 1);
        int* xE = xC + NF_C;
        build_csr(stream, fg_idx, NA_C, NF_C, xR, xC, xE);
        seg_mean_k<<<dim3((NF_C + 1) / 2), dim3(256), 0, stream>>>(
            hcur, atom_idx, xE, xR, S0, NF_C);
    }
    float* a2f_lin = S0 + (size_t)NF_C * DD;
    gemm_launch(stream, S0, nullptr, nullptr, nullptr, nullptr,
                a2f_W, a2f_b, nullptr, a2f_lin, NF_C, DD, DD);

    // fg CSR: lives at S0 + 3*NF*DD (above gn+gt), survives both fg layers
    int* fR = (int*)(S0 + (size_t)NF_C * DD * 3);
    int* fC = fR + (NF_C + 1);
    int* fE = fC + NF_C;
    build_csr(stream, fdst, EF_C, NF_C, fR, fC, fE);

    // 4) g = fg_x @ fg_emb_W + b + a2f_lin   -> S1[0, NF*DD)
    float* g = S1;
    gemm_launch(stream, fg_x, nullptr, nullptr, nullptr, nullptr,
                fg_emb_W, fg_emb_b, a2f_lin, g, NF_C, 73, DD);

    // 5) two fg GINE layers: eemb@S2, gn@S0[0,NF*DD), gt@S0[NF*DD,3*NF*DD)
    float* eemb = S2;
    float* gn   = S0;
    float* gt   = S0 + (size_t)NF_C * DD;
    for (int i = 0; i < 2; ++i) {
        gemm_launch(stream, fg_edge_attr, nullptr, nullptr, nullptr, nullptr,
                    fge_W + (size_t)i * 101 * DD, fge_b + i * DD, nullptr, eemb, EF_C, 101, DD);
        gine_agg_pre<<<dim3((NF_C + 1) / 2), dim3(256), 0, stream>>>(
            g, eemb, fsrc, fE, fR, gn, NF_C);
        gemm_launch(stream, gn, nullptr, nullptr, nullptr, nullptr,
                    fg_W1 + (size_t)i * DD * HH, fg_b1 + i * HH, nullptr, gt, NF_C, DD, HH);
        hipMemsetAsync(s_sum, 0, 512 * sizeof(float), stream);
        colstats<<<dim3((NF_C + 127) / 128), dim3(HH), 0, stream>>>(gt, NF_C, HH, s_sum, s_sq);
        bn_finalize<<<dim3(1), dim3(HH), 0, stream>>>(
            s_sum, s_sq, fg_g1 + i * HH, fg_be1 + i * HH, 1.f / NF_C, s_sc, s_sh, HH);
        gemm_launch(stream, gt, nullptr, nullptr, s_sc, s_sh,
                    fg_W2 + (size_t)i * HH * DD, fg_b2 + i * DD, nullptr, g, NF_C, HH, DD);
        hipMemsetAsync(s_sum, 0, 512 * sizeof(float), stream);
        colstats<<<dim3((NF_C + 127) / 128), dim3(DD), 0, stream>>>(g, NF_C, DD, s_sum, s_sq);
        bn_finalize<<<dim3(1), dim3(DD), 0, stream>>>(
            s_sum, s_sq, fbn_g + i * DD, fbn_b + i * DD, 1.f / NF_C, s_sc, s_sh, DD);
        bn_apply<<<dim3((NF_C * DD / 4 + 255) / 256), dim3(256), 0, stream>>>(
            g, s_sc, s_sh, (int)(i != 1), (size_t)NF_C * DD / 4);
    }

    // 6) final: out = seg_mean(g, fg_batch, NG); batch CSR transient in S2
    {
        int* bR = (int*)S2;
        int* bC = bR + (NG_C + 1);
        int* bE = bC + NG_C;
        build_csr(stream, fg_batch, NF_C, NG_C, bR, bC, bE);
        seg_mean_k<<<dim3((NG_C + 1) / 2), dim3(256), 0, stream>>>(
            g, nullptr, bE, bR, (float*)d_out, NG_C);
    }
}

// Round 4
// 2941.581 us; speedup vs baseline: 2.2054x; 2.2054x over previous
//
#include <hip/hip_runtime.h>
#include <cstddef>
#include <cstdint>

#define NA_C 200000
#define NF_C 50000
#define EA_C 800000
#define EF_C 200000
#define NG_C 4096
#define DD 128
#define HH 256

typedef unsigned short u16;
typedef unsigned int   u32;
typedef float f32x4 __attribute__((ext_vector_type(4)));
typedef short s16x8 __attribute__((ext_vector_type(8)));

__device__ inline float bf2f(u16 h) { return __uint_as_float(((u32)h) << 16); }
__device__ inline u16 f2bf(float f) {
    u32 u = __float_as_uint(f);
    return (u16)((u + 0x7fffu + ((u >> 16) & 1u)) >> 16);
}
__device__ inline float2 up2(u32 u) {
    return make_float2(__uint_as_float(u << 16), __uint_as_float(u & 0xffff0000u));
}
__device__ inline u32 pk2(float x, float y) { return (u32)f2bf(x) | ((u32)f2bf(y) << 16); }

// ---------------------------------------------------------------------------
// bf16 MFMA GEMM: C = op(A) @ Wt^T + bias [+ Cadd]
//   A [M,K] bf16 row-major (K % 32 == 0), Wt [Ntot,K] bf16 (pre-transposed W)
//   op: if iscale: a = relu(a*iscale[k] + ishift[k])  (fused BN+relu on input)
// 128x128 tile, BK=32, 256 thr = 4 waves, each wave 64x64 via 16 MFMA/K-step.
// Staging: r = tid>>1 covers ALL 128 rows; each thread stores 2 uint4 per
// buffer (full 8 KB tile — the R2 bug staged only half).
// Layouts per m89/m91: A-frag A[m=lane&15][k=quad*8+j]; B-frag Wt[n=lane&15][k];
// C/D col=lane&15, row=quad*4+reg.
// ---------------------------------------------------------------------------
__global__ __launch_bounds__(256) void gemm_b(
    const u16* __restrict__ A, const u16* __restrict__ Bt,
    const float* __restrict__ bias,
    const float* __restrict__ iscale, const float* __restrict__ ishift,
    const u16* __restrict__ Cadd, u16* __restrict__ C,
    int M, int K, int Ntot)
{
    __shared__ u16 As[4 * 128 * 8];   // [k8][row][j]
    __shared__ u16 Bs[4 * 128 * 8];
    const int tid  = threadIdx.x;
    const int wave = tid >> 6, lane = tid & 63;
    const int quad = lane >> 4, l15 = lane & 15;
    const int wm = (wave & 1) * 64, wn = (wave >> 1) * 64;
    const int m0 = blockIdx.y * 128, n0 = blockIdx.x * 128;
    const int r     = tid >> 1;        // 0..127 tile row
    const int cpair = (tid & 1) * 2;   // col-group base (each group = 8 u16)

    f32x4 acc[4][4];
#pragma unroll
    for (int i = 0; i < 4; ++i)
#pragma unroll
        for (int j = 0; j < 4; ++j) acc[i][j] = (f32x4)0.f;

    const int m = m0 + r;
    for (int k0 = 0; k0 < K; k0 += 32) {
#pragma unroll
        for (int j = 0; j < 2; ++j) {
            const int cg = cpair + j;
            uint4 av = make_uint4(0, 0, 0, 0);
            if (m < M) av = *(const uint4*)(A + (size_t)m * K + k0 + cg * 8);
            if (iscale) {
                u32* w = (u32*)&av;
#pragma unroll
                for (int q2 = 0; q2 < 4; ++q2) {
                    int kk = k0 + cg * 8 + q2 * 2;
                    float2 f = up2(w[q2]);
                    f.x = fmaxf(fmaf(f.x, iscale[kk],     ishift[kk]),     0.f);
                    f.y = fmaxf(fmaf(f.y, iscale[kk + 1], ishift[kk + 1]), 0.f);
                    w[q2] = pk2(f.x, f.y);
                }
            }
            *(uint4*)&As[(cg * 128 + r) * 8] = av;
        }
#pragma unroll
        for (int j = 0; j < 2; ++j) {
            const int cg = cpair + j;
            uint4 bv = *(const uint4*)(Bt + (size_t)(n0 + r) * K + k0 + cg * 8);
            *(uint4*)&Bs[(cg * 128 + r) * 8] = bv;
        }
        __syncthreads();

        s16x8 a[4], b[4];
#pragma unroll
        for (int mi = 0; mi < 4; ++mi)
            a[mi] = *(const s16x8*)&As[(quad * 128 + wm + mi * 16 + l15) * 8];
#pragma unroll
        for (int ni = 0; ni < 4; ++ni)
            b[ni] = *(const s16x8*)&Bs[(quad * 128 + wn + ni * 16 + l15) * 8];
#pragma unroll
        for (int mi = 0; mi < 4; ++mi)
#pragma unroll
            for (int ni = 0; ni < 4; ++ni)
                acc[mi][ni] = __builtin_amdgcn_mfma_f32_16x16x32_bf16(
                    a[mi], b[ni], acc[mi][ni], 0, 0, 0);
        __syncthreads();
    }

#pragma unroll
    for (int mi = 0; mi < 4; ++mi) {
        int rowb = m0 + wm + mi * 16 + quad * 4;
#pragma unroll
        for (int ni = 0; ni < 4; ++ni) {
            int col = n0 + wn + ni * 16 + l15;
            float bv = bias[col];
#pragma unroll
            for (int rr = 0; rr < 4; ++rr) {
                int row = rowb + rr;
                if (row < M) {
                    float v = acc[mi][ni][rr] + bv;
                    size_t idx = (size_t)row * Ntot + col;
                    if (Cadd) v += bf2f(Cadd[idx]);
                    C[idx] = f2bf(v);
                }
            }
        }
    }
}

static inline void gemm_launch(hipStream_t s, const u16* A, const u16* Bt,
    const float* bias, const float* iscale, const float* ishift,
    const u16* Cadd, u16* C, int M, int K, int Ntot)
{
    dim3 grid(Ntot / 128, (M + 127) / 128);
    gemm_b<<<grid, dim3(256), 0, s>>>(A, Bt, bias, iscale, ishift, Cadd, C, M, K, Ntot);
}

// fp32 [M,K] -> bf16 [M,Kp] zero-padded  (Kp2 = Kp/2 u32 per row)
__global__ void cvt_pad(const float* __restrict__ src, u32* __restrict__ dst,
                        int M, int K, int Kp2)
{
    int idx = blockIdx.x * 256 + threadIdx.x;
    if (idx >= M * Kp2) return;
    int row = idx / Kp2, c = (idx - row * Kp2) * 2;
    float a = (c < K)     ? src[(size_t)row * K + c]     : 0.f;
    float b = (c + 1 < K) ? src[(size_t)row * K + c + 1] : 0.f;
    dst[idx] = pk2(a, b);
}

// fp32 W [K,N] -> bf16 Wt [N,Kp] zero-padded
__global__ void prep_wt(const float* __restrict__ W, u16* __restrict__ Wt,
                        int K, int N, int Kp)
{
    int idx = blockIdx.x * 256 + threadIdx.x;
    if (idx >= N * Kp) return;
    int n = idx / Kp, k = idx - n * Kp;
    Wt[idx] = (k < K) ? f2bf(W[(size_t)k * N + n]) : (u16)0;
}

// ---------------------------------------------------------------------------
// CSR build
// ---------------------------------------------------------------------------
__global__ void hist_k(const int* __restrict__ idx, int n, int* __restrict__ deg)
{
    int i = blockIdx.x * 256 + threadIdx.x;
    if (i < n) atomicAdd(&deg[idx[i]], 1);
}

__global__ __launch_bounds__(1024) void scan_k(const int* __restrict__ deg,
                                               int* __restrict__ rowptr, int n)
{
    __shared__ int ss[1024];
    const int t = threadIdx.x;
    const int chunk = (n + 1023) >> 10;
    const int lo = min(t * chunk, n), hi = min(lo + chunk, n);
    int s = 0;
    for (int i = lo; i < hi; ++i) s += deg[i];
    ss[t] = s;
    __syncthreads();
    for (int off = 1; off < 1024; off <<= 1) {
        int v = (t >= off) ? ss[t - off] : 0;
        __syncthreads();
        ss[t] += v;
        __syncthreads();
    }
    int run = t ? ss[t - 1] : 0;
    for (int i = lo; i < hi; ++i) { rowptr[i] = run; run += deg[i]; }
    if (t == 1023) rowptr[n] = ss[1023];
}

// payload = (edge id, src[edge id])
__global__ void fill2_k(const int* __restrict__ idx, const int* __restrict__ src,
                        int n, int* __restrict__ cursor, int2* __restrict__ csr2)
{
    int i = blockIdx.x * 256 + threadIdx.x;
    if (i < n) {
        int p = atomicAdd(&cursor[idx[i]], 1);
        csr2[p] = make_int2(i, src[i]);
    }
}

// payload = map[i] (or i if map==nullptr)
__global__ void fillm_k(const int* __restrict__ idx, const int* __restrict__ map,
                        int n, int* __restrict__ cursor, int* __restrict__ csr)
{
    int i = blockIdx.x * 256 + threadIdx.x;
    if (i < n) {
        int p = atomicAdd(&cursor[idx[i]], 1);
        csr[p] = map ? map[i] : i;
    }
}

// ---------------------------------------------------------------------------
// Atom GINE aggregation (gather, bf16):
//   out[v] = x[v] + sum_e relu(x[src[e]] + attr[e] @ Wm + bm)
// wave per node, lane = 2 channels (u32 = bf16x2). 11x128 MLP in LDS.
// ---------------------------------------------------------------------------
__global__ __launch_bounds__(256) void gine_agg_atom_b(
    const u32* __restrict__ x2, const float* __restrict__ attr,
    const int2* __restrict__ csr2, const int* __restrict__ rowptr,
    const float* __restrict__ Wm, const float* __restrict__ bm,
    u32* __restrict__ out2, int n)
{
    __shared__ float2 sW[11][64];
    __shared__ float2 sb[64];
    for (int i = threadIdx.x; i < 11 * 64; i += 256) {
        int k = i >> 6, l = i & 63;
        sW[k][l] = make_float2(Wm[k * 128 + 2 * l], Wm[k * 128 + 2 * l + 1]);
    }
    if (threadIdx.x < 64)
        sb[threadIdx.x] = make_float2(bm[2 * threadIdx.x], bm[2 * threadIdx.x + 1]);
    __syncthreads();
    const int lane = threadIdx.x & 63;
    const int v = blockIdx.x * 4 + (threadIdx.x >> 6);
    if (v >= n) return;
    float2 acc = up2(x2[(size_t)v * 64 + lane]);
    const int e1 = rowptr[v + 1];
    for (int e = rowptr[v]; e < e1; ++e) {
        int2 p = csr2[e];
        const float* ar = attr + (size_t)p.x * 11;
        float m0 = sb[lane].x, m1 = sb[lane].y;
#pragma unroll
        for (int k = 0; k < 11; ++k) {
            float a = ar[k];
            m0 = fmaf(a, sW[k][lane].x, m0);
            m1 = fmaf(a, sW[k][lane].y, m1);
        }
        float2 s = up2(x2[(size_t)p.y * 64 + lane]);
        acc.x += fmaxf(s.x + m0, 0.f);
        acc.y += fmaxf(s.y + m1, 0.f);
    }
    out2[(size_t)v * 64 + lane] = pk2(acc.x, acc.y);
}

// fg aggregation with precomputed edge embeddings (bf16 rows gathered by eid)
__global__ __launch_bounds__(256) void gine_agg_pre_b(
    const u32* __restrict__ x2, const u32* __restrict__ eemb2,
    const int2* __restrict__ csr2, const int* __restrict__ rowptr,
    u32* __restrict__ out2, int n)
{
    const int lane = threadIdx.x & 63;
    const int v = blockIdx.x * 4 + (threadIdx.x >> 6);
    if (v >= n) return;
    float2 acc = up2(x2[(size_t)v * 64 + lane]);
    const int e1 = rowptr[v + 1];
    for (int e = rowptr[v]; e < e1; ++e) {
        int2 p = csr2[e];
        float2 m = up2(eemb2[(size_t)p.x * 64 + lane]);
        float2 s = up2(x2[(size_t)p.y * 64 + lane]);
        acc.x += fmaxf(m.x + s.x, 0.f);
        acc.y += fmaxf(m.y + s.y, 0.f);
    }
    out2[(size_t)v * 64 + lane] = pk2(acc.x, acc.y);
}

// segment mean (csr holds pre-mapped row ids), bf16 in -> bf16 out
__global__ __launch_bounds__(256) void seg_mean_b2b(
    const u32* __restrict__ x2, const int* __restrict__ csr,
    const int* __restrict__ rowptr, u32* __restrict__ out2, int n)
{
    const int lane = threadIdx.x & 63;
    const int v = blockIdx.x * 4 + (threadIdx.x >> 6);
    if (v >= n) return;
    const int e0 = rowptr[v], e1 = rowptr[v + 1];
    float2 acc = make_float2(0.f, 0.f);
    for (int e = e0; e < e1; ++e) {
        float2 s = up2(x2[(size_t)csr[e] * 64 + lane]);
        acc.x += s.x; acc.y += s.y;
    }
    float inv = 1.f / fmaxf((float)(e1 - e0), 1.f);
    out2[(size_t)v * 64 + lane] = pk2(acc.x * inv, acc.y * inv);
}

// segment mean, bf16 in -> fp32 out (final)
__global__ __launch_bounds__(256) void seg_mean_b2f(
    const u32* __restrict__ x2, const int* __restrict__ csr,
    const int* __restrict__ rowptr, float* __restrict__ out, int n)
{
    const int lane = threadIdx.x & 63;
    const int v = blockIdx.x * 4 + (threadIdx.x >> 6);
    if (v >= n) return;
    const int e0 = rowptr[v], e1 = rowptr[v + 1];
    float2 acc = make_float2(0.f, 0.f);
    for (int e = e0; e < e1; ++e) {
        float2 s = up2(x2[(size_t)csr[e] * 64 + lane]);
        acc.x += s.x; acc.y += s.y;
    }
    float inv = 1.f / fmaxf((float)(e1 - e0), 1.f);
    *(float2*)&out[(size_t)v * 128 + lane * 2] = make_float2(acc.x * inv, acc.y * inv);
}

// ---------------------------------------------------------------------------
// BN (two-pass) on bf16 tensors
// ---------------------------------------------------------------------------
__global__ void colstats_b(const u16* __restrict__ X, int M, int N,
                           float* __restrict__ sum, float* __restrict__ sumsq)
{
    int c = threadIdx.x;
    int r0 = blockIdx.x * 128;
    int rend = min(r0 + 128, M);
    float s = 0.f, q = 0.f;
    for (int r = r0; r < rend; ++r) {
        float v = bf2f(X[(size_t)r * N + c]);
        s += v;
        q = fmaf(v, v, q);
    }
    atomicAdd(&sum[c], s);
    atomicAdd(&sumsq[c], q);
}

__global__ void bn_finalize(const float* __restrict__ sum, const float* __restrict__ sumsq,
                            const float* __restrict__ g, const float* __restrict__ be,
                            float minv, float* __restrict__ sc, float* __restrict__ sh, int N)
{
    int c = threadIdx.x;
    if (c < N) {
        float m = sum[c] * minv;
        float v = fmaxf(sumsq[c] * minv - m * m, 0.f);
        float s = g[c] * rsqrtf(v + 1e-5f);
        sc[c] = s;
        sh[c] = fmaf(-m, s, be[c]);
    }
}

__global__ void bn_apply_b(u32* __restrict__ X2, const float* __restrict__ sc,
                           const float* __restrict__ sh, int relu, int N2, int total2)
{
    int i = blockIdx.x * 256 + threadIdx.x;
    if (i >= total2) return;
    int c = (i & (N2 - 1)) * 2;
    float2 f = up2(X2[i]);
    f.x = fmaf(f.x, sc[c],     sh[c]);
    f.y = fmaf(f.y, sc[c + 1], sh[c + 1]);
    if (relu) { f.x = fmaxf(f.x, 0.f); f.y = fmaxf(f.y, 0.f); }
    X2[i] = pk2(f.x, f.y);
}

// ---------------------------------------------------------------------------
extern "C" void kernel_launch(void* const* d_in, const int* in_sizes, int n_in,
                              void* d_out, int out_size, void* d_ws, size_t ws_size,
                              hipStream_t stream)
{
    const float* atom_x        = (const float*)d_in[0];
    const float* fg_x          = (const float*)d_in[1];
    const float* atom_edge_attr= (const float*)d_in[2];
    const float* fg_edge_attr  = (const float*)d_in[3];
    const float* atom_emb_W    = (const float*)d_in[4];
    const float* atom_emb_b    = (const float*)d_in[5];
    const float* fg_emb_W      = (const float*)d_in[6];
    const float* fg_emb_b      = (const float*)d_in[7];
    const float* bond_W        = (const float*)d_in[8];
    const float* bond_b        = (const float*)d_in[9];
    const float* ag_W1         = (const float*)d_in[10];
    const float* ag_b1         = (const float*)d_in[11];
    const float* ag_g1         = (const float*)d_in[12];
    const float* ag_be1        = (const float*)d_in[13];
    const float* ag_W2         = (const float*)d_in[14];
    const float* ag_b2         = (const float*)d_in[15];
    const float* abn_g         = (const float*)d_in[16];
    const float* abn_b         = (const float*)d_in[17];
    const float* fge_W         = (const float*)d_in[18];
    const float* fge_b         = (const float*)d_in[19];
    const float* fg_W1         = (const float*)d_in[20];
    const float* fg_b1         = (const float*)d_in[21];
    const float* fg_g1         = (const float*)d_in[22];
    const float* fg_be1        = (const float*)d_in[23];
    const float* fg_W2         = (const float*)d_in[24];
    const float* fg_b2         = (const float*)d_in[25];
    const float* fbn_g         = (const float*)d_in[26];
    const float* fbn_b         = (const float*)d_in[27];
    const float* a2f_W         = (const float*)d_in[28];
    const float* a2f_b         = (const float*)d_in[29];
    const int*   aei           = (const int*)d_in[30];
    const int*   fei           = (const int*)d_in[31];
    const int*   atom_idx      = (const int*)d_in[32];
    const int*   fg_idx        = (const int*)d_in[33];
    const int*   fg_batch      = (const int*)d_in[34];
    const int *asrc = aei, *adst = aei + EA_C;
    const int *fsrc = fei, *fdst = fei + EF_C;

    // ---- workspace carving (bytes) ----
    char* base = (char*)d_ws;
    const size_t SZ_H = (size_t)NA_C * DD * 2;        // 51.2 MB bf16 node slot
    u16* hA = (u16*)base;                             // h ping
    u16* hB = (u16*)(base + SZ_H);                    // h pong
    u16* TB = (u16*)(base + 2 * SZ_H);                // t (NA x 256 bf16, 102.4 MB)
    u16* XB = (u16*)(base + 2 * SZ_H + (size_t)NA_C * HH * 2);  // atom_x_bf / fg_attr_bf
    char* csrb = (char*)XB + SZ_H;                    // CSR area (16B aligned)
    int*  aR  = (int*)csrb;                           // rowptr (max NA+1)
    int*  aCu = aR + (NA_C + 2);                      // cursor (max NA) — +2 keeps aE2 8B-aligned
    int2* aE2 = (int2*)(aCu + NA_C);                  // payload (max EA int2), 8B-aligned
    char* wtb = (char*)(aE2 + EA_C);
    wtb = (char*)(((uintptr_t)wtb + 15) & ~(uintptr_t)15);   // 16B align for uint4 loads
    u16* WT_aemb = (u16*)wtb;                 wtb += 128 * 128 * 2;
    u16* WT_aW1  = (u16*)wtb;                 wtb += 3 * 256 * 128 * 2;
    u16* WT_aW2  = (u16*)wtb;                 wtb += 3 * 128 * 256 * 2;
    u16* WT_a2f  = (u16*)wtb;                 wtb += 128 * 128 * 2;
    u16* WT_femb = (u16*)wtb;                 wtb += 128 * 96 * 2;
    u16* WT_fge  = (u16*)wtb;                 wtb += 2 * 128 * 128 * 2;
    u16* WT_fW1  = (u16*)wtb;                 wtb += 2 * 256 * 128 * 2;
    u16* WT_fW2  = (u16*)wtb;                 wtb += 2 * 128 * 256 * 2;

    // BN stats scratch in tail of d_out (1024 floats; final write covers it)
    float* sm    = (float*)d_out + (size_t)NG_C * DD - 2048;
    float* s_sum = sm;
    float* s_sq  = sm + 256;
    float* s_sc  = sm + 512;
    float* s_sh  = sm + 768;

    // ---- weight prep (bf16, transposed, K zero-padded) ----
    {
        int g = (128 * 128 + 255) / 256;
        prep_wt<<<g, 256, 0, stream>>>(atom_emb_W, WT_aemb, 101, 128, 128);
        prep_wt<<<g, 256, 0, stream>>>(a2f_W, WT_a2f, 128, 128, 128);
        for (int i = 0; i < 3; ++i) {
            prep_wt<<<(256 * 128 + 255) / 256, 256, 0, stream>>>(
                ag_W1 + (size_t)i * 128 * 256, WT_aW1 + (size_t)i * 256 * 128, 128, 256, 128);
            prep_wt<<<(128 * 256 + 255) / 256, 256, 0, stream>>>(
                ag_W2 + (size_t)i * 256 * 128, WT_aW2 + (size_t)i * 128 * 256, 256, 128, 256);
        }
        prep_wt<<<(128 * 96 + 255) / 256, 256, 0, stream>>>(fg_emb_W, WT_femb, 73, 128, 96);
        for (int i = 0; i < 2; ++i) {
            prep_wt<<<g, 256, 0, stream>>>(
                fge_W + (size_t)i * 101 * 128, WT_fge + (size_t)i * 128 * 128, 101, 128, 128);
            prep_wt<<<(256 * 128 + 255) / 256, 256, 0, stream>>>(
                fg_W1 + (size_t)i * 128 * 256, WT_fW1 + (size_t)i * 256 * 128, 128, 256, 128);
            prep_wt<<<(128 * 256 + 255) / 256, 256, 0, stream>>>(
                fg_W2 + (size_t)i * 256 * 128, WT_fW2 + (size_t)i * 128 * 256, 256, 128, 256);
        }
    }

    // ---- atom CSR (dst-sorted, payload (eid, src)) ----
    hipMemsetAsync(aCu, 0, (size_t)NA_C * 4, stream);
    hist_k<<<(EA_C + 255) / 256, 256, 0, stream>>>(adst, EA_C, aCu);
    scan_k<<<1, 1024, 0, stream>>>(aCu, aR, NA_C);
    hipMemcpyAsync(aCu, aR, (size_t)NA_C * 4, hipMemcpyDeviceToDevice, stream);
    fill2_k<<<(EA_C + 255) / 256, 256, 0, stream>>>(adst, asrc, EA_C, aCu, aE2);

    // ---- atom_x -> bf16 padded [NA,128] ----
    cvt_pad<<<((size_t)NA_C * 64 + 255) / 256, 256, 0, stream>>>(atom_x, (u32*)XB, NA_C, 101, 64);

    // ---- atom embedding ----
    gemm_launch(stream, XB, WT_aemb, atom_emb_b, nullptr, nullptr, nullptr, hA, NA_C, 128, 128);

    // ---- 3 atom GINE layers (hA <-> hB ping-pong) ----
    u16* hc = hA;
    for (int i = 0; i < 3; ++i) {
        u16* hn = (hc == hA) ? hB : hA;
        gine_agg_atom_b<<<(NA_C + 3) / 4, 256, 0, stream>>>(
            (const u32*)hc, atom_edge_attr, aE2, aR,
            bond_W + (size_t)i * 11 * DD, bond_b + i * DD, (u32*)hn, NA_C);
        gemm_launch(stream, hn, WT_aW1 + (size_t)i * 256 * 128,
                    ag_b1 + i * HH, nullptr, nullptr, nullptr, TB, NA_C, 128, HH);
        hipMemsetAsync(s_sum, 0, 512 * sizeof(float), stream);
        colstats_b<<<(NA_C + 127) / 128, HH, 0, stream>>>(TB, NA_C, HH, s_sum, s_sq);
        bn_finalize<<<1, HH, 0, stream>>>(s_sum, s_sq, ag_g1 + i * HH, ag_be1 + i * HH,
                                          1.f / NA_C, s_sc, s_sh, HH);
        gemm_launch(stream, TB, WT_aW2 + (size_t)i * 128 * 256,
                    ag_b2 + i * DD, s_sc, s_sh, nullptr, hn, NA_C, 256, 128);
        hipMemsetAsync(s_sum, 0, 512 * sizeof(float), stream);
        colstats_b<<<(NA_C + 127) / 128, DD, 0, stream>>>(hn, NA_C, DD, s_sum, s_sq);
        bn_finalize<<<1, DD, 0, stream>>>(s_sum, s_sq, abn_g + i * DD, abn_b + i * DD,
                                          1.f / NA_C, s_sc, s_sh, DD);
        bn_apply_b<<<((size_t)NA_C * 64 + 255) / 256, 256, 0, stream>>>(
            (u32*)hn, s_sc, s_sh, (int)(i != 2), 64, NA_C * 64);
        hc = hn;
    }
    // hc == hB (h3)

    // ---- a2f: means = seg_mean(h3[atom_idx], fg_idx, NF) @ a2f_W + b ----
    {
        int* xR  = aR;                      // reuse CSR area (atom CSR dead)
        int* xCu = aCu;
        int* xE  = (int*)aE2;
        hipMemsetAsync(xCu, 0, (size_t)NF_C * 4, stream);
        hist_k<<<(NA_C + 255) / 256, 256, 0, stream>>>(fg_idx, NA_C, xCu);
        scan_k<<<1, 1024, 0, stream>>>(xCu, xR, NF_C);
        hipMemcpyAsync(xCu, xR, (size_t)NF_C * 4, hipMemcpyDeviceToDevice, stream);
        fillm_k<<<(NA_C + 255) / 256, 256, 0, stream>>>(fg_idx, atom_idx, NA_C, xCu, xE);
        seg_mean_b2b<<<(NF_C + 3) / 4, 256, 0, stream>>>((const u32*)hc, xE, xR, (u32*)hA, NF_C);
    }
    u16* means   = hA;                                  // [NF,128]
    u16* a2f_lin = hA + (size_t)NF_C * DD;              // [NF,128]
    gemm_launch(stream, means, WT_a2f, a2f_b, nullptr, nullptr, nullptr, a2f_lin, NF_C, 128, 128);

    // ---- fg embedding: g = fg_x @ femb + b + a2f_lin  (g @ hB) ----
    u16* fgx_bf = hA + (size_t)NF_C * DD * 2;           // [NF,96]
    cvt_pad<<<((size_t)NF_C * 48 + 255) / 256, 256, 0, stream>>>(fg_x, (u32*)fgx_bf, NF_C, 73, 48);
    u16* g = hB;
    gemm_launch(stream, fgx_bf, WT_femb, fg_emb_b, nullptr, nullptr, a2f_lin, g, NF_C, 96, 128);

    // ---- fg edge attr -> bf16 [EF,128]; fg CSR ----
    cvt_pad<<<((size_t)EF_C * 64 + 255) / 256, 256, 0, stream>>>(fg_edge_attr, (u32*)XB, EF_C, 101, 64);
    int*  fR  = aR;
    int*  fCu = aCu;
    int2* fE2 = aE2;
    hipMemsetAsync(fCu, 0, (size_t)NF_C * 4, stream);
    hist_k<<<(EF_C + 255) / 256, 256, 0, stream>>>(fdst, EF_C, fCu);
    scan_k<<<1, 1024, 0, stream>>>(fCu, fR, NF_C);
    hipMemcpyAsync(fCu, fR, (size_t)NF_C * 4, hipMemcpyDeviceToDevice, stream);
    fill2_k<<<(EF_C + 255) / 256, 256, 0, stream>>>(fdst, fsrc, EF_C, fCu, fE2);

    // ---- 2 fg GINE layers ----
    u16* eemb = TB;                                     // [EF,128] bf16
    u16* gn   = hA + (size_t)NF_C * DD * 2 + (size_t)NF_C * 96;  // [NF,128]
    u16* gt   = TB + (size_t)EF_C * DD;                 // [NF,256]
    for (int i = 0; i < 2; ++i) {
        gemm_launch(stream, XB, WT_fge + (size_t)i * 128 * 128,
                    fge_b + i * DD, nullptr, nullptr, nullptr, eemb, EF_C, 128, 128);
        gine_agg_pre_b<<<(NF_C + 3) / 4, 256, 0, stream>>>(
            (const u32*)g, (const u32*)eemb, fE2, fR, (u32*)gn, NF_C);
        gemm_launch(stream, gn, WT_fW1 + (size_t)i * 256 * 128,
                    fg_b1 + i * HH, nullptr, nullptr, nullptr, gt, NF_C, 128, HH);
        hipMemsetAsync(s_sum, 0, 512 * sizeof(float), stream);
        colstats_b<<<(NF_C + 127) / 128, HH, 0, stream>>>(gt, NF_C, HH, s_sum, s_sq);
        bn_finalize<<<1, HH, 0, stream>>>(s_sum, s_sq, fg_g1 + i * HH, fg_be1 + i * HH,
                                          1.f / NF_C, s_sc, s_sh, HH);
        gemm_launch(stream, gt, WT_fW2 + (size_t)i * 128 * 256,
                    fg_b2 + i * DD, s_sc, s_sh, nullptr, g, NF_C, 256, 128);
        hipMemsetAsync(s_sum, 0, 512 * sizeof(float), stream);
        colstats_b<<<(NF_C + 127) / 128, DD, 0, stream>>>(g, NF_C, DD, s_sum, s_sq);
        bn_finalize<<<1, DD, 0, stream>>>(s_sum, s_sq, fbn_g + i * DD, fbn_b + i * DD,
                                          1.f / NF_C, s_sc, s_sh, DD);
        bn_apply_b<<<((size_t)NF_C * 64 + 255) / 256, 256, 0, stream>>>(
            (u32*)g, s_sc, s_sh, (int)(i != 1), 64, NF_C * 64);
    }

    // ---- final seg_mean(g, fg_batch, NG) -> d_out fp32 ----
    {
        int* bR  = (int*)(gt + (size_t)NF_C * HH);      // past gt (dead)
        int* bCu = bR + (NG_C + 1);
        int* bE  = bCu + NG_C;
        hipMemsetAsync(bCu, 0, (size_t)NG_C * 4, stream);
        hist_k<<<(NF_C + 255) / 256, 256, 0, stream>>>(fg_batch, NF_C, bCu);
        scan_k<<<1, 1024, 0, stream>>>(bCu, bR, NG_C);
        hipMemcpyAsync(bCu, bR, (size_t)NG_C * 4, hipMemcpyDeviceToDevice, stream);
        fillm_k<<<(NF_C + 255) / 256, 256, 0, stream>>>(fg_batch, nullptr, NF_C, bCu, bE);
        seg_mean_b2f<<<(NG_C + 3) / 4, 256, 0, stream>>>(
            (const u32*)g, bE, bR, (float*)d_out, NG_C);
    }
}

// Round 5
// 2508.350 us; speedup vs baseline: 2.5864x; 1.1727x over previous
//
#include <hip/hip_runtime.h>
#include <cstddef>
#include <cstdint>

#define NA_C 200000
#define NF_C 50000
#define EA_C 800000
#define EF_C 200000
#define NG_C 4096
#define DD 128
#define HH 256
#define SC_CHUNK 2048

typedef unsigned short u16;
typedef unsigned int   u32;
typedef float f32x4 __attribute__((ext_vector_type(4)));
typedef short s16x8 __attribute__((ext_vector_type(8)));

__device__ inline float bf2f(u16 h) { return __uint_as_float(((u32)h) << 16); }
__device__ inline u16 f2bf(float f) {
    u32 u = __float_as_uint(f);
    return (u16)((u + 0x7fffu + ((u >> 16) & 1u)) >> 16);
}
__device__ inline float2 up2(u32 u) {
    return make_float2(__uint_as_float(u << 16), __uint_as_float(u & 0xffff0000u));
}
__device__ inline u32 pk2(float x, float y) { return (u32)f2bf(x) | ((u32)f2bf(y) << 16); }

// ---------------------------------------------------------------------------
// bf16 MFMA GEMM: C = op(A) @ Wt^T + bias [+ Cadd]
//   A [M,K] bf16 row-major (K % 32 == 0), Wt [Ntot,K] bf16 (pre-transposed W)
//   op: if iscale: a = relu(a*iscale[k] + ishift[k])  (fused BN+relu on input)
// 128x128 tile, BK=32, 256 thr = 4 waves, each wave 64x64 via 16 MFMA/K-step.
// Staging: r = tid>>1 covers ALL 128 rows; 2 uint4 per thread per buffer.
// Layouts per m89/m91: A-frag A[m=lane&15][k=quad*8+j]; B-frag Wt[n=lane&15][k];
// C/D col=lane&15, row=quad*4+reg.
// ---------------------------------------------------------------------------
__global__ __launch_bounds__(256) void gemm_b(
    const u16* __restrict__ A, const u16* __restrict__ Bt,
    const float* __restrict__ bias,
    const float* __restrict__ iscale, const float* __restrict__ ishift,
    const u16* __restrict__ Cadd, u16* __restrict__ C,
    int M, int K, int Ntot)
{
    __shared__ u16 As[4 * 128 * 8];   // [k8][row][j]
    __shared__ u16 Bs[4 * 128 * 8];
    const int tid  = threadIdx.x;
    const int wave = tid >> 6, lane = tid & 63;
    const int quad = lane >> 4, l15 = lane & 15;
    const int wm = (wave & 1) * 64, wn = (wave >> 1) * 64;
    const int m0 = blockIdx.y * 128, n0 = blockIdx.x * 128;
    const int r     = tid >> 1;        // 0..127 tile row
    const int cpair = (tid & 1) * 2;   // col-group base (each group = 8 u16)

    f32x4 acc[4][4];
#pragma unroll
    for (int i = 0; i < 4; ++i)
#pragma unroll
        for (int j = 0; j < 4; ++j) acc[i][j] = (f32x4)0.f;

    const int m = m0 + r;
    for (int k0 = 0; k0 < K; k0 += 32) {
#pragma unroll
        for (int j = 0; j < 2; ++j) {
            const int cg = cpair + j;
            uint4 av = make_uint4(0, 0, 0, 0);
            if (m < M) av = *(const uint4*)(A + (size_t)m * K + k0 + cg * 8);
            if (iscale) {
                u32* w = (u32*)&av;
#pragma unroll
                for (int q2 = 0; q2 < 4; ++q2) {
                    int kk = k0 + cg * 8 + q2 * 2;
                    float2 f = up2(w[q2]);
                    f.x = fmaxf(fmaf(f.x, iscale[kk],     ishift[kk]),     0.f);
                    f.y = fmaxf(fmaf(f.y, iscale[kk + 1], ishift[kk + 1]), 0.f);
                    w[q2] = pk2(f.x, f.y);
                }
            }
            *(uint4*)&As[(cg * 128 + r) * 8] = av;
        }
#pragma unroll
        for (int j = 0; j < 2; ++j) {
            const int cg = cpair + j;
            uint4 bv = *(const uint4*)(Bt + (size_t)(n0 + r) * K + k0 + cg * 8);
            *(uint4*)&Bs[(cg * 128 + r) * 8] = bv;
        }
        __syncthreads();

        s16x8 a[4], b[4];
#pragma unroll
        for (int mi = 0; mi < 4; ++mi)
            a[mi] = *(const s16x8*)&As[(quad * 128 + wm + mi * 16 + l15) * 8];
#pragma unroll
        for (int ni = 0; ni < 4; ++ni)
            b[ni] = *(const s16x8*)&Bs[(quad * 128 + wn + ni * 16 + l15) * 8];
#pragma unroll
        for (int mi = 0; mi < 4; ++mi)
#pragma unroll
            for (int ni = 0; ni < 4; ++ni)
                acc[mi][ni] = __builtin_amdgcn_mfma_f32_16x16x32_bf16(
                    a[mi], b[ni], acc[mi][ni], 0, 0, 0);
        __syncthreads();
    }

#pragma unroll
    for (int mi = 0; mi < 4; ++mi) {
        int rowb = m0 + wm + mi * 16 + quad * 4;
#pragma unroll
        for (int ni = 0; ni < 4; ++ni) {
            int col = n0 + wn + ni * 16 + l15;
            float bv = bias[col];
#pragma unroll
            for (int rr = 0; rr < 4; ++rr) {
                int row = rowb + rr;
                if (row < M) {
                    float v = acc[mi][ni][rr] + bv;
                    size_t idx = (size_t)row * Ntot + col;
                    if (Cadd) v += bf2f(Cadd[idx]);
                    C[idx] = f2bf(v);
                }
            }
        }
    }
}

static inline void gemm_launch(hipStream_t s, const u16* A, const u16* Bt,
    const float* bias, const float* iscale, const float* ishift,
    const u16* Cadd, u16* C, int M, int K, int Ntot)
{
    dim3 grid(Ntot / 128, (M + 127) / 128);
    gemm_b<<<grid, dim3(256), 0, s>>>(A, Bt, bias, iscale, ishift, Cadd, C, M, K, Ntot);
}

// fp32 [M,K] -> bf16 [M,Kp] zero-padded  (Kp2 = Kp/2 u32 per row)
__global__ void cvt_pad(const float* __restrict__ src, u32* __restrict__ dst,
                        int M, int K, int Kp2)
{
    int idx = blockIdx.x * 256 + threadIdx.x;
    if (idx >= M * Kp2) return;
    int row = idx / Kp2, c = (idx - row * Kp2) * 2;
    float a = (c < K)     ? src[(size_t)row * K + c]     : 0.f;
    float b = (c + 1 < K) ? src[(size_t)row * K + c + 1] : 0.f;
    dst[idx] = pk2(a, b);
}

// fp32 W [K,N] -> bf16 Wt [N,Kp] zero-padded
__global__ void prep_wt(const float* __restrict__ W, u16* __restrict__ Wt,
                        int K, int N, int Kp)
{
    int idx = blockIdx.x * 256 + threadIdx.x;
    if (idx >= N * Kp) return;
    int n = idx / Kp, k = idx - n * Kp;
    Wt[idx] = (k < K) ? f2bf(W[(size_t)k * N + n]) : (u16)0;
}

// ---------------------------------------------------------------------------
// CSR build: histogram -> 3-phase multi-block exclusive scan -> fill
// (R3's single-block scan_k was 320 us — one block, latency-bound. This is
//  fully parallel: part-sums -> top scan (<=256 partials) -> emit.)
// ---------------------------------------------------------------------------
__global__ void hist_k(const int* __restrict__ idx, int n, int* __restrict__ deg)
{
    int i = blockIdx.x * 256 + threadIdx.x;
    if (i < n) atomicAdd(&deg[idx[i]], 1);
}

__global__ __launch_bounds__(256) void scan_part_k(const int* __restrict__ deg, int n,
                                                   int* __restrict__ bsum)
{
    __shared__ int ts[256];
    const int t = threadIdx.x;
    const int base = blockIdx.x * SC_CHUNK + t * 8;
    int s = 0;
#pragma unroll
    for (int j = 0; j < 8; ++j) { int i = base + j; if (i < n) s += deg[i]; }
    ts[t] = s;
    __syncthreads();
    for (int off = 128; off > 0; off >>= 1) {
        if (t < off) ts[t] += ts[t + off];
        __syncthreads();
    }
    if (t == 0) bsum[blockIdx.x] = ts[0];
}

__global__ __launch_bounds__(256) void scan_top_k(int* __restrict__ bsum, int nb)
{
    __shared__ int ss[256];
    const int t = threadIdx.x;
    int v = (t < nb) ? bsum[t] : 0;
    ss[t] = v;
    __syncthreads();
    for (int off = 1; off < 256; off <<= 1) {
        int u = (t >= off) ? ss[t - off] : 0;
        __syncthreads();
        ss[t] += u;
        __syncthreads();
    }
    if (t < nb) bsum[t] = ss[t] - v;   // exclusive
}

__global__ __launch_bounds__(256) void scan_emit_k(const int* __restrict__ deg, int n,
                                                   const int* __restrict__ bsum,
                                                   int* __restrict__ rowptr)
{
    __shared__ int ts[256];
    const int t = threadIdx.x;
    const int base = blockIdx.x * SC_CHUNK + t * 8;
    int d[8], loc[8], s = 0;
#pragma unroll
    for (int j = 0; j < 8; ++j) {
        int i = base + j;
        d[j] = (i < n) ? deg[i] : 0;
        loc[j] = s;
        s += d[j];
    }
    ts[t] = s;
    __syncthreads();
    for (int off = 1; off < 256; off <<= 1) {
        int u = (t >= off) ? ts[t - off] : 0;
        __syncthreads();
        ts[t] += u;
        __syncthreads();
    }
    const int off0 = bsum[blockIdx.x] + (ts[t] - s);
#pragma unroll
    for (int j = 0; j < 8; ++j) {
        int i = base + j;
        if (i < n) {
            rowptr[i] = off0 + loc[j];
            if (i == n - 1) rowptr[n] = off0 + loc[j] + d[j];
        }
    }
}

static void csr_prefix(hipStream_t s, const int* idx, int ne, int nbkt,
                       int* rowptr, int* cursor, int* bsum)
{
    hipMemsetAsync(cursor, 0, (size_t)nbkt * 4, s);
    hist_k<<<(ne + 255) / 256, 256, 0, s>>>(idx, ne, cursor);
    int nblk = (nbkt + SC_CHUNK - 1) / SC_CHUNK;
    scan_part_k<<<nblk, 256, 0, s>>>(cursor, nbkt, bsum);
    scan_top_k<<<1, 256, 0, s>>>(bsum, nblk);
    scan_emit_k<<<nblk, 256, 0, s>>>(cursor, nbkt, bsum, rowptr);
    hipMemcpyAsync(cursor, rowptr, (size_t)nbkt * 4, hipMemcpyDeviceToDevice, s);
}

// payload = (edge id, src[edge id])
__global__ void fill2_k(const int* __restrict__ idx, const int* __restrict__ src,
                        int n, int* __restrict__ cursor, int2* __restrict__ csr2)
{
    int i = blockIdx.x * 256 + threadIdx.x;
    if (i < n) {
        int p = atomicAdd(&cursor[idx[i]], 1);
        csr2[p] = make_int2(i, src[i]);
    }
}

// payload = map[i] (or i if map==nullptr)
__global__ void fillm_k(const int* __restrict__ idx, const int* __restrict__ map,
                        int n, int* __restrict__ cursor, int* __restrict__ csr)
{
    int i = blockIdx.x * 256 + threadIdx.x;
    if (i < n) {
        int p = atomicAdd(&cursor[idx[i]], 1);
        csr[p] = map ? map[i] : i;
    }
}

// ---------------------------------------------------------------------------
// Atom GINE aggregation (gather, bf16):
//   out[v] = x[v] + sum_e relu(x[src[e]] + attr[e] @ Wm + bm)
// wave per node, lane = 2 channels (u32 = bf16x2). 11x128 MLP in LDS.
// ---------------------------------------------------------------------------
__global__ __launch_bounds__(256) void gine_agg_atom_b(
    const u32* __restrict__ x2, const float* __restrict__ attr,
    const int2* __restrict__ csr2, const int* __restrict__ rowptr,
    const float* __restrict__ Wm, const float* __restrict__ bm,
    u32* __restrict__ out2, int n)
{
    __shared__ float2 sW[11][64];
    __shared__ float2 sb[64];
    for (int i = threadIdx.x; i < 11 * 64; i += 256) {
        int k = i >> 6, l = i & 63;
        sW[k][l] = make_float2(Wm[k * 128 + 2 * l], Wm[k * 128 + 2 * l + 1]);
    }
    if (threadIdx.x < 64)
        sb[threadIdx.x] = make_float2(bm[2 * threadIdx.x], bm[2 * threadIdx.x + 1]);
    __syncthreads();
    const int lane = threadIdx.x & 63;
    const int v = blockIdx.x * 4 + (threadIdx.x >> 6);
    if (v >= n) return;
    float2 acc = up2(x2[(size_t)v * 64 + lane]);
    const int e1 = rowptr[v + 1];
    for (int e = rowptr[v]; e < e1; ++e) {
        int2 p = csr2[e];
        const float* ar = attr + (size_t)p.x * 11;
        float m0 = sb[lane].x, m1 = sb[lane].y;
#pragma unroll
        for (int k = 0; k < 11; ++k) {
            float a = ar[k];
            m0 = fmaf(a, sW[k][lane].x, m0);
            m1 = fmaf(a, sW[k][lane].y, m1);
        }
        float2 s = up2(x2[(size_t)p.y * 64 + lane]);
        acc.x += fmaxf(s.x + m0, 0.f);
        acc.y += fmaxf(s.y + m1, 0.f);
    }
    out2[(size_t)v * 64 + lane] = pk2(acc.x, acc.y);
}

// fg aggregation with precomputed edge embeddings (bf16 rows gathered by eid)
__global__ __launch_bounds__(256) void gine_agg_pre_b(
    const u32* __restrict__ x2, const u32* __restrict__ eemb2,
    const int2* __restrict__ csr2, const int* __restrict__ rowptr,
    u32* __restrict__ out2, int n)
{
    const int lane = threadIdx.x & 63;
    const int v = blockIdx.x * 4 + (threadIdx.x >> 6);
    if (v >= n) return;
    float2 acc = up2(x2[(size_t)v * 64 + lane]);
    const int e1 = rowptr[v + 1];
    for (int e = rowptr[v]; e < e1; ++e) {
        int2 p = csr2[e];
        float2 m = up2(eemb2[(size_t)p.x * 64 + lane]);
        float2 s = up2(x2[(size_t)p.y * 64 + lane]);
        acc.x += fmaxf(m.x + s.x, 0.f);
        acc.y += fmaxf(m.y + s.y, 0.f);
    }
    out2[(size_t)v * 64 + lane] = pk2(acc.x, acc.y);
}

// segment mean (csr holds pre-mapped row ids), bf16 in -> bf16 out
__global__ __launch_bounds__(256) void seg_mean_b2b(
    const u32* __restrict__ x2, const int* __restrict__ csr,
    const int* __restrict__ rowptr, u32* __restrict__ out2, int n)
{
    const int lane = threadIdx.x & 63;
    const int v = blockIdx.x * 4 + (threadIdx.x >> 6);
    if (v >= n) return;
    const int e0 = rowptr[v], e1 = rowptr[v + 1];
    float2 acc = make_float2(0.f, 0.f);
    for (int e = e0; e < e1; ++e) {
        float2 s = up2(x2[(size_t)csr[e] * 64 + lane]);
        acc.x += s.x; acc.y += s.y;
    }
    float inv = 1.f / fmaxf((float)(e1 - e0), 1.f);
    out2[(size_t)v * 64 + lane] = pk2(acc.x * inv, acc.y * inv);
}

// segment mean, bf16 in -> fp32 out (final)
__global__ __launch_bounds__(256) void seg_mean_b2f(
    const u32* __restrict__ x2, const int* __restrict__ csr,
    const int* __restrict__ rowptr, float* __restrict__ out, int n)
{
    const int lane = threadIdx.x & 63;
    const int v = blockIdx.x * 4 + (threadIdx.x >> 6);
    if (v >= n) return;
    const int e0 = rowptr[v], e1 = rowptr[v + 1];
    float2 acc = make_float2(0.f, 0.f);
    for (int e = e0; e < e1; ++e) {
        float2 s = up2(x2[(size_t)csr[e] * 64 + lane]);
        acc.x += s.x; acc.y += s.y;
    }
    float inv = 1.f / fmaxf((float)(e1 - e0), 1.f);
    *(float2*)&out[(size_t)v * 128 + lane * 2] = make_float2(acc.x * inv, acc.y * inv);
}

// ---------------------------------------------------------------------------
// BN (two-pass) on bf16 tensors
// ---------------------------------------------------------------------------
__global__ void colstats_b(const u16* __restrict__ X, int M, int N,
                           float* __restrict__ sum, float* __restrict__ sumsq)
{
    int c = threadIdx.x;
    int r0 = blockIdx.x * 128;
    int rend = min(r0 + 128, M);
    float s = 0.f, q = 0.f;
    for (int r = r0; r < rend; ++r) {
        float v = bf2f(X[(size_t)r * N + c]);
        s += v;
        q = fmaf(v, v, q);
    }
    atomicAdd(&sum[c], s);
    atomicAdd(&sumsq[c], q);
}

__global__ void bn_finalize(const float* __restrict__ sum, const float* __restrict__ sumsq,
                            const float* __restrict__ g, const float* __restrict__ be,
                            float minv, float* __restrict__ sc, float* __restrict__ sh, int N)
{
    int c = threadIdx.x;
    if (c < N) {
        float m = sum[c] * minv;
        float v = fmaxf(sumsq[c] * minv - m * m, 0.f);
        float s = g[c] * rsqrtf(v + 1e-5f);
        sc[c] = s;
        sh[c] = fmaf(-m, s, be[c]);
    }
}

__global__ void bn_apply_b(u32* __restrict__ X2, const float* __restrict__ sc,
                           const float* __restrict__ sh, int relu, int N2, int total2)
{
    int i = blockIdx.x * 256 + threadIdx.x;
    if (i >= total2) return;
    int c = (i & (N2 - 1)) * 2;
    float2 f = up2(X2[i]);
    f.x = fmaf(f.x, sc[c],     sh[c]);
    f.y = fmaf(f.y, sc[c + 1], sh[c + 1]);
    if (relu) { f.x = fmaxf(f.x, 0.f); f.y = fmaxf(f.y, 0.f); }
    X2[i] = pk2(f.x, f.y);
}

// ---------------------------------------------------------------------------
extern "C" void kernel_launch(void* const* d_in, const int* in_sizes, int n_in,
                              void* d_out, int out_size, void* d_ws, size_t ws_size,
                              hipStream_t stream)
{
    const float* atom_x        = (const float*)d_in[0];
    const float* fg_x          = (const float*)d_in[1];
    const float* atom_edge_attr= (const float*)d_in[2];
    const float* fg_edge_attr  = (const float*)d_in[3];
    const float* atom_emb_W    = (const float*)d_in[4];
    const float* atom_emb_b    = (const float*)d_in[5];
    const float* fg_emb_W      = (const float*)d_in[6];
    const float* fg_emb_b      = (const float*)d_in[7];
    const float* bond_W        = (const float*)d_in[8];
    const float* bond_b        = (const float*)d_in[9];
    const float* ag_W1         = (const float*)d_in[10];
    const float* ag_b1         = (const float*)d_in[11];
    const float* ag_g1         = (const float*)d_in[12];
    const float* ag_be1        = (const float*)d_in[13];
    const float* ag_W2         = (const float*)d_in[14];
    const float* ag_b2         = (const float*)d_in[15];
    const float* abn_g         = (const float*)d_in[16];
    const float* abn_b         = (const float*)d_in[17];
    const float* fge_W         = (const float*)d_in[18];
    const float* fge_b         = (const float*)d_in[19];
    const float* fg_W1         = (const float*)d_in[20];
    const float* fg_b1         = (const float*)d_in[21];
    const float* fg_g1         = (const float*)d_in[22];
    const float* fg_be1        = (const float*)d_in[23];
    const float* fg_W2         = (const float*)d_in[24];
    const float* fg_b2         = (const float*)d_in[25];
    const float* fbn_g         = (const float*)d_in[26];
    const float* fbn_b         = (const float*)d_in[27];
    const float* a2f_W         = (const float*)d_in[28];
    const float* a2f_b         = (const float*)d_in[29];
    const int*   aei           = (const int*)d_in[30];
    const int*   fei           = (const int*)d_in[31];
    const int*   atom_idx      = (const int*)d_in[32];
    const int*   fg_idx        = (const int*)d_in[33];
    const int*   fg_batch      = (const int*)d_in[34];
    const int *asrc = aei, *adst = aei + EA_C;
    const int *fsrc = fei, *fdst = fei + EF_C;

    // ---- workspace carving (bytes) ----
    char* base = (char*)d_ws;
    const size_t SZ_H = (size_t)NA_C * DD * 2;        // 51.2 MB bf16 node slot
    u16* hA = (u16*)base;                             // h ping
    u16* hB = (u16*)(base + SZ_H);                    // h pong
    u16* TB = (u16*)(base + 2 * SZ_H);                // t (NA x 256 bf16, 102.4 MB)
    u16* XB = (u16*)(base + 2 * SZ_H + (size_t)NA_C * HH * 2);  // atom_x_bf / fg_attr_bf
    char* csrb = (char*)XB + SZ_H;                    // CSR area (16B aligned)
    int*  aR  = (int*)csrb;                           // rowptr (max NA+1)
    int*  aCu = aR + (NA_C + 2);                      // cursor/deg (max NA)
    int*  bS  = aCu + NA_C;                           // scan partials (256)
    int2* aE2 = (int2*)(bS + 258);                    // payload (max EA int2); total ints before = 2*NA+260 (even -> 8B aligned)
    char* wtb = (char*)(aE2 + EA_C);
    wtb = (char*)(((uintptr_t)wtb + 15) & ~(uintptr_t)15);   // 16B align for uint4 loads
    u16* WT_aemb = (u16*)wtb;                 wtb += 128 * 128 * 2;
    u16* WT_aW1  = (u16*)wtb;                 wtb += 3 * 256 * 128 * 2;
    u16* WT_aW2  = (u16*)wtb;                 wtb += 3 * 128 * 256 * 2;
    u16* WT_a2f  = (u16*)wtb;                 wtb += 128 * 128 * 2;
    u16* WT_femb = (u16*)wtb;                 wtb += 128 * 96 * 2;
    u16* WT_fge  = (u16*)wtb;                 wtb += 2 * 128 * 128 * 2;
    u16* WT_fW1  = (u16*)wtb;                 wtb += 2 * 256 * 128 * 2;
    u16* WT_fW2  = (u16*)wtb;                 wtb += 2 * 128 * 256 * 2;

    // BN stats scratch in tail of d_out (1024 floats; final write covers it)
    float* sm    = (float*)d_out + (size_t)NG_C * DD - 2048;
    float* s_sum = sm;
    float* s_sq  = sm + 256;
    float* s_sc  = sm + 512;
    float* s_sh  = sm + 768;

    // ---- weight prep (bf16, transposed, K zero-padded) ----
    {
        int g = (128 * 128 + 255) / 256;
        prep_wt<<<g, 256, 0, stream>>>(atom_emb_W, WT_aemb, 101, 128, 128);
        prep_wt<<<g, 256, 0, stream>>>(a2f_W, WT_a2f, 128, 128, 128);
        for (int i = 0; i < 3; ++i) {
            prep_wt<<<(256 * 128 + 255) / 256, 256, 0, stream>>>(
                ag_W1 + (size_t)i * 128 * 256, WT_aW1 + (size_t)i * 256 * 128, 128, 256, 128);
            prep_wt<<<(128 * 256 + 255) / 256, 256, 0, stream>>>(
                ag_W2 + (size_t)i * 256 * 128, WT_aW2 + (size_t)i * 128 * 256, 256, 128, 256);
        }
        prep_wt<<<(128 * 96 + 255) / 256, 256, 0, stream>>>(fg_emb_W, WT_femb, 73, 128, 96);
        for (int i = 0; i < 2; ++i) {
            prep_wt<<<g, 256, 0, stream>>>(
                fge_W + (size_t)i * 101 * 128, WT_fge + (size_t)i * 128 * 128, 101, 128, 128);
            prep_wt<<<(256 * 128 + 255) / 256, 256, 0, stream>>>(
                fg_W1 + (size_t)i * 128 * 256, WT_fW1 + (size_t)i * 256 * 128, 128, 256, 128);
            prep_wt<<<(128 * 256 + 255) / 256, 256, 0, stream>>>(
                fg_W2 + (size_t)i * 256 * 128, WT_fW2 + (size_t)i * 128 * 256, 256, 128, 256);
        }
    }

    // ---- atom CSR (dst-sorted, payload (eid, src)) ----
    csr_prefix(stream, adst, EA_C, NA_C, aR, aCu, bS);
    fill2_k<<<(EA_C + 255) / 256, 256, 0, stream>>>(adst, asrc, EA_C, aCu, aE2);

    // ---- atom_x -> bf16 padded [NA,128] ----
    cvt_pad<<<((size_t)NA_C * 64 + 255) / 256, 256, 0, stream>>>(atom_x, (u32*)XB, NA_C, 101, 64);

    // ---- atom embedding ----
    gemm_launch(stream, XB, WT_aemb, atom_emb_b, nullptr, nullptr, nullptr, hA, NA_C, 128, 128);

    // ---- 3 atom GINE layers (hA <-> hB ping-pong) ----
    u16* hc = hA;
    for (int i = 0; i < 3; ++i) {
        u16* hn = (hc == hA) ? hB : hA;
        gine_agg_atom_b<<<(NA_C + 3) / 4, 256, 0, stream>>>(
            (const u32*)hc, atom_edge_attr, aE2, aR,
            bond_W + (size_t)i * 11 * DD, bond_b + i * DD, (u32*)hn, NA_C);
        gemm_launch(stream, hn, WT_aW1 + (size_t)i * 256 * 128,
                    ag_b1 + i * HH, nullptr, nullptr, nullptr, TB, NA_C, 128, HH);
        hipMemsetAsync(s_sum, 0, 512 * sizeof(float), stream);
        colstats_b<<<(NA_C + 127) / 128, HH, 0, stream>>>(TB, NA_C, HH, s_sum, s_sq);
        bn_finalize<<<1, HH, 0, stream>>>(s_sum, s_sq, ag_g1 + i * HH, ag_be1 + i * HH,
                                          1.f / NA_C, s_sc, s_sh, HH);
        gemm_launch(stream, TB, WT_aW2 + (size_t)i * 128 * 256,
                    ag_b2 + i * DD, s_sc, s_sh, nullptr, hn, NA_C, 256, 128);
        hipMemsetAsync(s_sum, 0, 512 * sizeof(float), stream);
        colstats_b<<<(NA_C + 127) / 128, DD, 0, stream>>>(hn, NA_C, DD, s_sum, s_sq);
        bn_finalize<<<1, DD, 0, stream>>>(s_sum, s_sq, abn_g + i * DD, abn_b + i * DD,
                                          1.f / NA_C, s_sc, s_sh, DD);
        bn_apply_b<<<((size_t)NA_C * 64 + 255) / 256, 256, 0, stream>>>(
            (u32*)hn, s_sc, s_sh, (int)(i != 2), 64, NA_C * 64);
        hc = hn;
    }
    // hc == hB (h3)

    // ---- a2f: means = seg_mean(h3[atom_idx], fg_idx, NF) @ a2f_W + b ----
    {
        int* xE = (int*)aE2;
        csr_prefix(stream, fg_idx, NA_C, NF_C, aR, aCu, bS);
        fillm_k<<<(NA_C + 255) / 256, 256, 0, stream>>>(fg_idx, atom_idx, NA_C, aCu, xE);
        seg_mean_b2b<<<(NF_C + 3) / 4, 256, 0, stream>>>((const u32*)hc, xE, aR, (u32*)hA, NF_C);
    }
    u16* means   = hA;                                  // [NF,128]
    u16* a2f_lin = hA + (size_t)NF_C * DD;              // [NF,128]
    gemm_launch(stream, means, WT_a2f, a2f_b, nullptr, nullptr, nullptr, a2f_lin, NF_C, 128, 128);

    // ---- fg embedding: g = fg_x @ femb + b + a2f_lin  (g @ hB) ----
    u16* fgx_bf = hA + (size_t)NF_C * DD * 2;           // [NF,96]
    cvt_pad<<<((size_t)NF_C * 48 + 255) / 256, 256, 0, stream>>>(fg_x, (u32*)fgx_bf, NF_C, 73, 48);
    u16* g = hB;
    gemm_launch(stream, fgx_bf, WT_femb, fg_emb_b, nullptr, nullptr, a2f_lin, g, NF_C, 96, 128);

    // ---- fg edge attr -> bf16 [EF,128]; fg CSR ----
    cvt_pad<<<((size_t)EF_C * 64 + 255) / 256, 256, 0, stream>>>(fg_edge_attr, (u32*)XB, EF_C, 101, 64);
    csr_prefix(stream, fdst, EF_C, NF_C, aR, aCu, bS);
    fill2_k<<<(EF_C + 255) / 256, 256, 0, stream>>>(fdst, fsrc, EF_C, aCu, aE2);

    // ---- 2 fg GINE layers ----
    u16* eemb = TB;                                     // [EF,128] bf16
    u16* gn   = hA + (size_t)NF_C * DD * 2 + (size_t)NF_C * 96;  // [NF,128]
    u16* gt   = TB + (size_t)EF_C * DD;                 // [NF,256]
    for (int i = 0; i < 2; ++i) {
        gemm_launch(stream, XB, WT_fge + (size_t)i * 128 * 128,
                    fge_b + i * DD, nullptr, nullptr, nullptr, eemb, EF_C, 128, 128);
        gine_agg_pre_b<<<(NF_C + 3) / 4, 256, 0, stream>>>(
            (const u32*)g, (const u32*)eemb, aE2, aR, (u32*)gn, NF_C);
        gemm_launch(stream, gn, WT_fW1 + (size_t)i * 256 * 128,
                    fg_b1 + i * HH, nullptr, nullptr, nullptr, gt, NF_C, 128, HH);
        hipMemsetAsync(s_sum, 0, 512 * sizeof(float), stream);
        colstats_b<<<(NF_C + 127) / 128, HH, 0, stream>>>(gt, NF_C, HH, s_sum, s_sq);
        bn_finalize<<<1, HH, 0, stream>>>(s_sum, s_sq, fg_g1 + i * HH, fg_be1 + i * HH,
                                          1.f / NF_C, s_sc, s_sh, HH);
        gemm_launch(stream, gt, WT_fW2 + (size_t)i * 128 * 256,
                    fg_b2 + i * DD, s_sc, s_sh, nullptr, g, NF_C, 256, 128);
        hipMemsetAsync(s_sum, 0, 512 * sizeof(float), stream);
        colstats_b<<<(NF_C + 127) / 128, DD, 0, stream>>>(g, NF_C, DD, s_sum, s_sq);
        bn_finalize<<<1, DD, 0, stream>>>(s_sum, s_sq, fbn_g + i * DD, fbn_b + i * DD,
                                          1.f / NF_C, s_sc, s_sh, DD);
        bn_apply_b<<<((size_t)NF_C * 64 + 255) / 256, 256, 0, stream>>>(
            (u32*)g, s_sc, s_sh, (int)(i != 1), 64, NF_C * 64);
    }

    // ---- final seg_mean(g, fg_batch, NG) -> d_out fp32 ----
    // batch CSR transient past gt in TB (dead region); reuse global bS for scan
    {
        int* bR  = (int*)(gt + (size_t)NF_C * HH);
        int* bCu = bR + (NG_C + 1);
        int* bE  = bCu + NG_C;
        csr_prefix(stream, fg_batch, NF_C, NG_C, bR, bCu, bS);
        fillm_k<<<(NF_C + 255) / 256, 256, 0, stream>>>(fg_batch, nullptr, NF_C, bCu, bE);
        seg_mean_b2f<<<(NG_C + 3) / 4, 256, 0, stream>>>(
            (const u32*)g, bE, bR, (float*)d_out, NG_C);
    }
}